// Round 2
// baseline (77.196 us; speedup 1.0000x reference)
//
#include <hip/hip_runtime.h>
#include <cstdint>

// Problem constants (B=1024, S=4096, P=512)
constexpr int B_ = 1024;
constexpr int S_ = 4096;
constexpr int P_ = 512;
constexpr int NSCAT = 512;   // scatter blocks
constexpr int NRED  = 16;    // reduce blocks (16 x 32 bins = 512)

// ---------------------------------------------------------------------------
// Kernel A: per-block histogram of (sum ds, count) over P=512 bins.
// 512 blocks x 256 threads x 32 elements = B*S exactly.
// Per-WAVE LDS sub-histograms (4 copies) kill inter-wave atomic contention.
// Output: part[block][1024] interleaved {sum[bin], cnt[bin]} pairs,
// written coalesced as float4 — NO global atomics.
// ---------------------------------------------------------------------------
__global__ __launch_bounds__(256) void scatter_kernel(
    const int* __restrict__ idx, const float* __restrict__ ds,
    float* __restrict__ part) {
  __shared__ float lsum[4][P_];
  __shared__ int   lcnt[4][P_];
  const int t = threadIdx.x;
  const int w = t >> 6;
#pragma unroll
  for (int c = 0; c < 4; ++c) {
    lsum[c][t] = 0.f; lsum[c][t + 256] = 0.f;
    lcnt[c][t] = 0;   lcnt[c][t + 256] = 0;
  }
  __syncthreads();

  float* __restrict__ ms = lsum[w];
  int*   __restrict__ mc = lcnt[w];
  const size_t base = (size_t)blockIdx.x * 8192 + (size_t)t * 4;
#pragma unroll
  for (int k = 0; k < 8; ++k) {
    const size_t off = base + (size_t)k * 1024;
    int4   iv = *reinterpret_cast<const int4*>(idx + off);
    float4 dv = *reinterpret_cast<const float4*>(ds + off);
    atomicAdd(&ms[iv.x], dv.x); atomicAdd(&mc[iv.x], 1);
    atomicAdd(&ms[iv.y], dv.y); atomicAdd(&mc[iv.y], 1);
    atomicAdd(&ms[iv.z], dv.z); atomicAdd(&mc[iv.z], 1);
    atomicAdd(&ms[iv.w], dv.w); atomicAdd(&mc[iv.w], 1);
  }
  __syncthreads();

  // thread t flushes bins 2t and 2t+1 as one float4 (coalesced, deterministic)
  const int b0 = 2 * t, b1 = 2 * t + 1;
  float4 ov;
  ov.x = lsum[0][b0] + lsum[1][b0] + lsum[2][b0] + lsum[3][b0];
  ov.y = (float)(lcnt[0][b0] + lcnt[1][b0] + lcnt[2][b0] + lcnt[3][b0]);
  ov.z = lsum[0][b1] + lsum[1][b1] + lsum[2][b1] + lsum[3][b1];
  ov.w = (float)(lcnt[0][b1] + lcnt[1][b1] + lcnt[2][b1] + lcnt[3][b1]);
  *reinterpret_cast<float4*>(part + (size_t)blockIdx.x * 1024 + 4 * t) = ov;
}

// ---------------------------------------------------------------------------
// Kernel B: reduce partials + finalize table + dn scalars.
// 16 blocks x 256 threads; block bid owns bins [bid*32, bid*32+32).
// Each block reduces its 64 interleaved columns over 512 partial rows
// (coalesced 256B-per-row-segment reads), then:
//   table[p] = touched ? (sum_in+gsum)/max(cnt_in+gcnt,1) : dur_in[p]
//   block 0 additionally computes dn_new, trunc scalars.
// ---------------------------------------------------------------------------
__global__ __launch_bounds__(256) void reduce_finalize_kernel(
    const float* __restrict__ part,
    const float* __restrict__ sum_in, const float* __restrict__ cnt_in,
    const float* __restrict__ dur_in, const float* __restrict__ rv,
    const float* __restrict__ dn_in,
    float* __restrict__ table, float* __restrict__ scal,
    float* __restrict__ out_tail /* d_out + B*S : 512 table + 1 dn */) {
  __shared__ float sred[4][64];
  __shared__ float s26[7], c26[7], raw26[7];

  const int t   = threadIdx.x;
  const int bid = blockIdx.x;
  const int col = bid * 64 + (t & 63);   // interleaved column in [0,1024)
  const int wr  = t >> 6;                // starting row (wave id)

  float acc = 0.f;
  for (int b = wr; b < NSCAT; b += 4)
    acc += part[(size_t)b * 1024 + col];
  sred[wr][t & 63] = acc;
  __syncthreads();

  if (t < 32) {
    const int bin = bid * 32 + t;
    const int e = 2 * t, o = 2 * t + 1;
    const float gsum = sred[0][e] + sred[1][e] + sred[2][e] + sred[3][e];
    const float gcnt = sred[0][o] + sred[1][o] + sred[2][o] + sred[3][o];
    const float sn = gsum + sum_in[bin];
    const float cn = gcnt + cnt_in[bin];
    const float tv = (gcnt > 0.f) ? sn / fmaxf(cn, 1.f) : dur_in[bin];
    table[bin]    = tv;
    out_tail[bin] = tv;
    if (bid == 0 && bin >= 2 && bin < 7) {
      s26[bin] = sn; c26[bin] = cn; raw26[bin] = gcnt;
    }
  }
  __syncthreads();

  if (bid == 0 && t == 0) {
    float ss = 0.f, cc = 0.f, rc = 0.f;
    for (int i = 2; i < 7; ++i) { ss += s26[i]; cc += c26[i]; rc += raw26[i]; }
    const bool has26 = rc > 0.f;
    const float dnn = has26 ? (ss / cc) : dn_in[0];
    out_tail[P_] = dnn;                  // dn_new
    const float dni = truncf(dnn);
    scal[0] = dni;
    scal[1] = dni - truncf(rv[0] * dnn); // num = int(dn) - int(rv*dn)
  }
}

// ---------------------------------------------------------------------------
// Kernel C: per-row gather + rescale. 1 block (256 thr) per row; 16 cols/thread.
// ---------------------------------------------------------------------------
__global__ __launch_bounds__(256) void eval_kernel(
    const int* __restrict__ idx, const float* __restrict__ table,
    const float* __restrict__ scal, const int* __restrict__ padp,
    float* __restrict__ out) {
  __shared__ float tbl[P_];
  __shared__ int   red_a[4], red_b[4], red_c[4];
  __shared__ int   bcast[3];  // n, dmax, denom

  const int t   = threadIdx.x;
  const int row = blockIdx.x;
  tbl[t]       = table[t];
  tbl[t + 256] = table[t + 256];
  const int pad = padp[0];
  __syncthreads();

  const int* __restrict__ rowidx = idx + (size_t)row * S_;
  int d[16];
  int jfirst = 0x7fffffff;
  int dmax   = 0x80000000;

#pragma unroll
  for (int k = 0; k < 4; ++k) {
    const int j0 = k * 1024 + t * 4;
    int4 iv = *reinterpret_cast<const int4*>(rowidx + j0);
    const int ivm[4] = {iv.x, iv.y, iv.z, iv.w};
#pragma unroll
    for (int m = 0; m < 4; ++m) {
      const int j = j0 + m;
      const int dd = (int)tbl[ivm[m]];  // trunc-toward-zero, values >= 0
      d[k * 4 + m] = dd;
      if (j >= 1) {
        if (ivm[m] == pad && j < jfirst) jfirst = j;
        if (dd > dmax) dmax = dd;
      }
    }
  }

  // phase-1 reduce: min(jfirst), max(dmax) over 256 threads
  const int wid = t >> 6, lane = t & 63;
  int a = jfirst, b = dmax;
#pragma unroll
  for (int o = 32; o > 0; o >>= 1) {
    a = min(a, __shfl_down(a, o));
    b = max(b, __shfl_down(b, o));
  }
  if (lane == 0) { red_a[wid] = a; red_b[wid] = b; }
  __syncthreads();
  if (t == 0) {
    int na = min(min(red_a[0], red_a[1]), min(red_a[2], red_a[3]));
    int nb = max(max(red_b[0], red_b[1]), max(red_b[2], red_b[3]));
    bcast[0] = (na == 0x7fffffff) ? 1 : na;   // n
    bcast[1] = nb;                            // row max dur (j>=1)
  }
  __syncthreads();
  const int n       = bcast[0];
  const int dmaxall = bcast[1];

  // phase-2 reduce: denom = sum of d[j] for 1 <= j < n
  int dsum = 0;
#pragma unroll
  for (int k = 0; k < 4; ++k) {
    const int j0 = k * 1024 + t * 4;
#pragma unroll
    for (int m = 0; m < 4; ++m) {
      const int j = j0 + m;
      if (j >= 1 && j < n) dsum += d[k * 4 + m];
    }
  }
#pragma unroll
  for (int o = 32; o > 0; o >>= 1) dsum += __shfl_down(dsum, o);
  if (lane == 0) red_c[wid] = dsum;
  __syncthreads();
  if (t == 0) bcast[2] = red_c[0] + red_c[1] + red_c[2] + red_c[3];
  __syncthreads();
  const int denom = bcast[2];

  const float dni = scal[0];
  const float num = scal[1];
  const float denomf = (float)denom;
  const float rc = (n == 1) ? 1.0f
                            : fminf(1.0f, num / (denomf > 0.f ? denomf : 1.0f));
  const int delta = max(dmaxall, 1);
  const int dur0  = max(1, (int)dni - delta);

  float* __restrict__ rowout = out + (size_t)row * S_;
#pragma unroll
  for (int k = 0; k < 4; ++k) {
    const int j0 = k * 1024 + t * 4;
    float4 ov;
    float* o = reinterpret_cast<float*>(&ov);
#pragma unroll
    for (int m = 0; m < 4; ++m) {
      const int j = j0 + m;
      const int dd = d[k * 4 + m];
      int v;
      if (j == 0)      v = dur0;
      else if (j < n)  v = max(1, (int)truncf(rc * (float)dd));
      else             v = dd;
      o[m] = (float)v;
    }
    *reinterpret_cast<float4*>(rowout + j0) = ov;
  }
}

// ---------------------------------------------------------------------------
extern "C" void kernel_launch(void* const* d_in, const int* in_sizes, int n_in,
                              void* d_out, int out_size, void* d_ws, size_t ws_size,
                              hipStream_t stream) {
  const int*   idx    = (const int*)d_in[0];
  const float* ds     = (const float*)d_in[1];
  const float* sum_in = (const float*)d_in[2];
  const float* cnt_in = (const float*)d_in[3];
  const float* dur_in = (const float*)d_in[4];
  const float* rv     = (const float*)d_in[5];
  const float* dn     = (const float*)d_in[6];
  const int*   pad    = (const int*)d_in[7];

  float* out = (float*)d_out;

  float* part  = (float*)d_ws;            // [512][1024] = 2 MB
  float* table = part + (size_t)NSCAT * 1024;  // [512]
  float* scal  = table + P_;              // [2] : dn_i, num

  scatter_kernel<<<NSCAT, 256, 0, stream>>>(idx, ds, part);
  reduce_finalize_kernel<<<NRED, 256, 0, stream>>>(part, sum_in, cnt_in,
                                                   dur_in, rv, dn, table, scal,
                                                   out + (size_t)B_ * S_);
  eval_kernel<<<1024, 256, 0, stream>>>(idx, table, scal, pad, out);
}

// Round 3
// 42.969 us; speedup vs baseline: 1.7966x; 1.7966x over previous
//
#include <hip/hip_runtime.h>
#include <cstdint>

// Problem constants (B=1024, S=4096, P=512)
constexpr int B_ = 1024;
constexpr int S_ = 4096;
constexpr int P_ = 512;
constexpr int NSCAT = 512;   // scatter blocks (partial-histogram rows)

// ---------------------------------------------------------------------------
// Kernel A: per-block histogram of (sum ds, count) over P=512 bins.
// 512 blocks x 256 threads x 32 elements = B*S exactly.
// Per-WAVE LDS sub-histograms (4 copies) kill inter-wave atomic contention.
// Output: part[block][1024] interleaved {sum[bin], cnt[bin]} pairs
// (col 2p = sum of bin p, col 2p+1 = cnt of bin p), coalesced float4 stores.
// ---------------------------------------------------------------------------
__global__ __launch_bounds__(256) void scatter_kernel(
    const int* __restrict__ idx, const float* __restrict__ ds,
    float* __restrict__ part) {
  __shared__ float lsum[4][P_];
  __shared__ int   lcnt[4][P_];
  const int t = threadIdx.x;
  const int w = t >> 6;
#pragma unroll
  for (int c = 0; c < 4; ++c) {
    lsum[c][t] = 0.f; lsum[c][t + 256] = 0.f;
    lcnt[c][t] = 0;   lcnt[c][t + 256] = 0;
  }
  __syncthreads();

  float* __restrict__ ms = lsum[w];
  int*   __restrict__ mc = lcnt[w];
  const size_t base = (size_t)blockIdx.x * 8192 + (size_t)t * 4;
#pragma unroll
  for (int k = 0; k < 8; ++k) {
    const size_t off = base + (size_t)k * 1024;
    int4   iv = *reinterpret_cast<const int4*>(idx + off);
    float4 dv = *reinterpret_cast<const float4*>(ds + off);
    atomicAdd(&ms[iv.x], dv.x); atomicAdd(&mc[iv.x], 1);
    atomicAdd(&ms[iv.y], dv.y); atomicAdd(&mc[iv.y], 1);
    atomicAdd(&ms[iv.z], dv.z); atomicAdd(&mc[iv.z], 1);
    atomicAdd(&ms[iv.w], dv.w); atomicAdd(&mc[iv.w], 1);
  }
  __syncthreads();

  // thread t flushes bins 2t and 2t+1 as one float4 (coalesced, deterministic)
  const int b0 = 2 * t, b1 = 2 * t + 1;
  float4 ov;
  ov.x = lsum[0][b0] + lsum[1][b0] + lsum[2][b0] + lsum[3][b0];
  ov.y = (float)(lcnt[0][b0] + lcnt[1][b0] + lcnt[2][b0] + lcnt[3][b0]);
  ov.z = lsum[0][b1] + lsum[1][b1] + lsum[2][b1] + lsum[3][b1];
  ov.w = (float)(lcnt[0][b1] + lcnt[1][b1] + lcnt[2][b1] + lcnt[3][b1]);
  *reinterpret_cast<float4*>(part + (size_t)blockIdx.x * 1024 + 4 * t) = ov;
}

// ---------------------------------------------------------------------------
// Kernel B: one block per BIN (512 blocks x 256 threads).
// Thread t loads float2 {sum,cnt} at rows t and t+256 of its bin's column
// pair (2 independent 8B loads), then LDS + shfl tree reduction.
// Thread 0 finalizes table[p]; bins 2..6 also dump {sn, cn, raw_cnt} to
// stats[] for the dn computation (done in eval, since bins span blocks).
// ---------------------------------------------------------------------------
__global__ __launch_bounds__(256) void reduce_finalize_kernel(
    const float* __restrict__ part,
    const float* __restrict__ sum_in, const float* __restrict__ cnt_in,
    const float* __restrict__ dur_in,
    float* __restrict__ table, float* __restrict__ stats,
    float* __restrict__ out_tail /* d_out + B*S : 512 table values */) {
  __shared__ float2 sred[256];
  const int t = threadIdx.x;
  const int p = blockIdx.x;

  const float2 a = *reinterpret_cast<const float2*>(
      part + (size_t)t * 1024 + 2 * p);
  const float2 b = *reinterpret_cast<const float2*>(
      part + (size_t)(t + 256) * 1024 + 2 * p);
  sred[t] = make_float2(a.x + b.x, a.y + b.y);
  __syncthreads();

  if (t < 128) {
    sred[t].x += sred[t + 128].x;
    sred[t].y += sred[t + 128].y;
  }
  __syncthreads();

  if (t < 64) {
    float ss = sred[t].x + sred[t + 64].x;
    float cc = sred[t].y + sred[t + 64].y;
#pragma unroll
    for (int o = 32; o > 0; o >>= 1) {
      ss += __shfl_down(ss, o);
      cc += __shfl_down(cc, o);
    }
    if (t == 0) {
      const float sn = ss + sum_in[p];
      const float cn = cc + cnt_in[p];
      const float tv = (cc > 0.f) ? sn / fmaxf(cn, 1.f) : dur_in[p];
      table[p]    = tv;
      out_tail[p] = tv;
      if (p >= 2 && p < 7) {
        stats[p - 2]      = sn;   // sum_new
        stats[5 + p - 2]  = cn;   // cnt_new
        stats[10 + p - 2] = cc;   // raw scatter count (for has_26)
      }
    }
  }
}

// ---------------------------------------------------------------------------
// Kernel C: per-row gather + rescale. 1 block (256 thr) per row; 16 cols/thr.
// Thread 0 of each block computes the dn scalars from stats (cheap, uniform);
// block 0 also writes dn_new to the output tail.
// ---------------------------------------------------------------------------
__global__ __launch_bounds__(256) void eval_kernel(
    const int* __restrict__ idx, const float* __restrict__ table,
    const float* __restrict__ stats, const float* __restrict__ rv,
    const float* __restrict__ dn_in, const int* __restrict__ padp,
    float* __restrict__ out) {
  __shared__ float tbl[P_];
  __shared__ int   red_a[4], red_b[4], red_c[4];
  __shared__ int   bcast[3];   // n, dmax, denom
  __shared__ float fbcast[2];  // dni, num

  const int t   = threadIdx.x;
  const int row = blockIdx.x;
  tbl[t]       = table[t];
  tbl[t + 256] = table[t + 256];
  const int pad = padp[0];

  if (t == 0) {
    float ss = 0.f, cc = 0.f, rc = 0.f;
#pragma unroll
    for (int i = 0; i < 5; ++i) {
      ss += stats[i]; cc += stats[5 + i]; rc += stats[10 + i];
    }
    const float dnn = (rc > 0.f) ? (ss / cc) : dn_in[0];
    const float dni = truncf(dnn);
    fbcast[0] = dni;
    fbcast[1] = dni - truncf(rv[0] * dnn);   // num = int(dn) - int(rv*dn)
    if (row == 0) out[(size_t)B_ * S_ + P_] = dnn;  // dn_new output
  }
  __syncthreads();

  const int* __restrict__ rowidx = idx + (size_t)row * S_;
  int d[16];
  int jfirst = 0x7fffffff;
  int dmax   = 0x80000000;

#pragma unroll
  for (int k = 0; k < 4; ++k) {
    const int j0 = k * 1024 + t * 4;
    int4 iv = *reinterpret_cast<const int4*>(rowidx + j0);
    const int ivm[4] = {iv.x, iv.y, iv.z, iv.w};
#pragma unroll
    for (int m = 0; m < 4; ++m) {
      const int j = j0 + m;
      const int dd = (int)tbl[ivm[m]];  // trunc-toward-zero, values >= 0
      d[k * 4 + m] = dd;
      if (j >= 1) {
        if (ivm[m] == pad && j < jfirst) jfirst = j;
        if (dd > dmax) dmax = dd;
      }
    }
  }

  // phase-1 reduce: min(jfirst), max(dmax) over 256 threads
  const int wid = t >> 6, lane = t & 63;
  int a = jfirst, b = dmax;
#pragma unroll
  for (int o = 32; o > 0; o >>= 1) {
    a = min(a, __shfl_down(a, o));
    b = max(b, __shfl_down(b, o));
  }
  if (lane == 0) { red_a[wid] = a; red_b[wid] = b; }
  __syncthreads();
  if (t == 0) {
    int na = min(min(red_a[0], red_a[1]), min(red_a[2], red_a[3]));
    int nb = max(max(red_b[0], red_b[1]), max(red_b[2], red_b[3]));
    bcast[0] = (na == 0x7fffffff) ? 1 : na;   // n
    bcast[1] = nb;                            // row max dur (j>=1)
  }
  __syncthreads();
  const int n       = bcast[0];
  const int dmaxall = bcast[1];

  // phase-2 reduce: denom = sum of d[j] for 1 <= j < n
  int dsum = 0;
#pragma unroll
  for (int k = 0; k < 4; ++k) {
    const int j0 = k * 1024 + t * 4;
#pragma unroll
    for (int m = 0; m < 4; ++m) {
      const int j = j0 + m;
      if (j >= 1 && j < n) dsum += d[k * 4 + m];
    }
  }
#pragma unroll
  for (int o = 32; o > 0; o >>= 1) dsum += __shfl_down(dsum, o);
  if (lane == 0) red_c[wid] = dsum;
  __syncthreads();
  if (t == 0) bcast[2] = red_c[0] + red_c[1] + red_c[2] + red_c[3];
  __syncthreads();
  const int denom = bcast[2];

  const float dni = fbcast[0];
  const float num = fbcast[1];
  const float denomf = (float)denom;
  const float rc = (n == 1) ? 1.0f
                            : fminf(1.0f, num / (denomf > 0.f ? denomf : 1.0f));
  const int delta = max(dmaxall, 1);
  const int dur0  = max(1, (int)dni - delta);

  float* __restrict__ rowout = out + (size_t)row * S_;
#pragma unroll
  for (int k = 0; k < 4; ++k) {
    const int j0 = k * 1024 + t * 4;
    float4 ov;
    float* o = reinterpret_cast<float*>(&ov);
#pragma unroll
    for (int m = 0; m < 4; ++m) {
      const int j = j0 + m;
      const int dd = d[k * 4 + m];
      int v;
      if (j == 0)      v = dur0;
      else if (j < n)  v = max(1, (int)truncf(rc * (float)dd));
      else             v = dd;
      o[m] = (float)v;
    }
    *reinterpret_cast<float4*>(rowout + j0) = ov;
  }
}

// ---------------------------------------------------------------------------
extern "C" void kernel_launch(void* const* d_in, const int* in_sizes, int n_in,
                              void* d_out, int out_size, void* d_ws, size_t ws_size,
                              hipStream_t stream) {
  const int*   idx    = (const int*)d_in[0];
  const float* ds     = (const float*)d_in[1];
  const float* sum_in = (const float*)d_in[2];
  const float* cnt_in = (const float*)d_in[3];
  const float* dur_in = (const float*)d_in[4];
  const float* rv     = (const float*)d_in[5];
  const float* dn     = (const float*)d_in[6];
  const int*   pad    = (const int*)d_in[7];

  float* out = (float*)d_out;

  float* part  = (float*)d_ws;                 // [512][1024] = 2 MB
  float* table = part + (size_t)NSCAT * 1024;  // [512]
  float* stats = table + P_;                   // [15] : sn[5], cn[5], raw[5]

  scatter_kernel<<<NSCAT, 256, 0, stream>>>(idx, ds, part);
  reduce_finalize_kernel<<<P_, 256, 0, stream>>>(part, sum_in, cnt_in, dur_in,
                                                 table, stats,
                                                 out + (size_t)B_ * S_);
  eval_kernel<<<1024, 256, 0, stream>>>(idx, table, stats, rv, dn, pad, out);
}